// Round 5
// baseline (399.586 us; speedup 1.0000x reference)
//
#include <hip/hip_runtime.h>
#include <hip/hip_bf16.h>

typedef __bf16 bf16;
typedef __bf16 bf16x4 __attribute__((ext_vector_type(4)));
typedef __bf16 bf16x8 __attribute__((ext_vector_type(8)));
typedef float f32x4 __attribute__((ext_vector_type(4)));
typedef float f32x16 __attribute__((ext_vector_type(16)));

#define MFMA16(a, b, c) __builtin_amdgcn_mfma_f32_16x16x32_bf16((a), (b), (c), 0, 0, 0)
#define MFMA32(a, b, c) __builtin_amdgcn_mfma_f32_32x32x16_bf16((a), (b), (c), 0, 0, 0)

#if __has_builtin(__builtin_amdgcn_exp2f)
#define EXP2(x) __builtin_amdgcn_exp2f(x)
#else
#define EXP2(x) exp2f(x)
#endif

constexpr int EMBED = 1024;
constexpr int HEADS = 16;
constexpr int HD = 64;
constexpr int SEQ = 2048;
constexpr int SFT = 72;    // proj per-wave transpose stride
constexpr int SXT = 136;   // proj V-transpose stride (128 cols + 8)

// softmax scale 1/sqrt(1024) folded with log2(e); applied to Wq conversion
#define QSCALE 0.04508422082f

// ---------------- QKV per-head projections (fused weight conversion) -------
// Block = 128 rows (rows = (n,l,h) flat), 4 waves x 32 rows. Weights read as
// fp32 and converted in-register (L1/L2-hot). Q/K epilogue is a per-wave LDS
// transpose (no barriers); V epilogue is a block LDS transpose -> Vt[n,h,d,l]
// with 16B stores. Also converts Wo -> bf16 (slice per block).
__global__ __launch_bounds__(256) void proj_kernel(
    const float* __restrict__ Vx, const float* __restrict__ Kx, const float* __restrict__ Qx,
    const float* __restrict__ Wv, const float* __restrict__ Wk, const float* __restrict__ Wq,
    const float* __restrict__ Wo,
    bf16* __restrict__ Vt, bf16* __restrict__ Kp, bf16* __restrict__ Qp,
    bf16* __restrict__ Wob) {
    __shared__ __align__(16) bf16 sU[4 * 32 * SFT];  // union: per-wave sT / block sXT
    int t = threadIdx.x, lane = t & 63, wq = t >> 6;
    int m = lane & 15, q8 = lane >> 4;
    int blockbase = blockIdx.x * 128;
    int rb = blockbase + wq * 32;

    // Wo slice conversion: 1024 elems per block, 4 per thread
    {
        int off = blockIdx.x * 1024 + t * 4;
        float4 w4 = *(const float4*)(Wo + off);
        bf16x4 o;
        o[0] = (bf16)w4.x; o[1] = (bf16)w4.y; o[2] = (bf16)w4.z; o[3] = (bf16)w4.w;
        *(bf16x4*)(Wob + off) = o;
    }

    const float* Xs[3] = {Qx, Kx, Vx};
    const float* Ws[3] = {Wq, Wk, Wv};
    f32x4 z = {0.f, 0.f, 0.f, 0.f};

    for (int ts = 0; ts < 3; ts++) {
        float sc = (ts == 0) ? QSCALE : 1.0f;
        // B frags: W[e][d] fp32 -> bf16 in-register
        bf16x8 bfr[4][2];
        for (int nt = 0; nt < 4; nt++)
            for (int c = 0; c < 2; c++) {
                const float* s = Ws[ts] + (nt * 16 + m) * 64 + c * 32 + q8 * 8;
                float4 x0 = *(const float4*)s;
                float4 x1 = *(const float4*)(s + 4);
                bf16x8 b;
                b[0] = (bf16)(x0.x * sc); b[1] = (bf16)(x0.y * sc);
                b[2] = (bf16)(x0.z * sc); b[3] = (bf16)(x0.w * sc);
                b[4] = (bf16)(x1.x * sc); b[5] = (bf16)(x1.y * sc);
                b[6] = (bf16)(x1.z * sc); b[7] = (bf16)(x1.w * sc);
                bfr[nt][c] = b;
            }
        // A frags: X rows, fp32 -> bf16 in-register
        bf16x8 af[2][2];
        for (int mt = 0; mt < 2; mt++)
            for (int c = 0; c < 2; c++) {
                const float* s = Xs[ts] + (size_t)(rb + mt * 16 + m) * 64 + c * 32 + q8 * 8;
                float4 x0 = *(const float4*)s;
                float4 x1 = *(const float4*)(s + 4);
                bf16x8 a;
                a[0] = (bf16)x0.x; a[1] = (bf16)x0.y; a[2] = (bf16)x0.z; a[3] = (bf16)x0.w;
                a[4] = (bf16)x1.x; a[5] = (bf16)x1.y; a[6] = (bf16)x1.z; a[7] = (bf16)x1.w;
                af[mt][c] = a;
            }
        f32x4 acc[2][4];
        for (int a = 0; a < 2; a++)
            for (int b = 0; b < 4; b++) acc[a][b] = z;
        for (int c = 0; c < 2; c++)
            for (int mt = 0; mt < 2; mt++)
                for (int nt = 0; nt < 4; nt++)
                    acc[mt][nt] = MFMA16(af[mt][c], bfr[nt][c], acc[mt][nt]);

        if (ts < 2) {
            // per-wave transpose (DS ops in-order within a wave; no barrier)
            bf16* sTw = sU + wq * 32 * SFT;
            for (int mt = 0; mt < 2; mt++)
                for (int nt = 0; nt < 4; nt++)
                    for (int j = 0; j < 4; j++)
                        sTw[(mt * 16 + q8 * 4 + j) * SFT + nt * 16 + m] = (bf16)acc[mt][nt][j];
            int r = lane >> 1, half = lane & 1;
            int R = rb + r;
            int h = R & 15, l = (R >> 4) & 2047, n = R >> 15;
            bf16* dst = ((ts == 0) ? Qp : Kp) +
                        ((size_t)(n * HEADS + h) * SEQ + l) * HD + half * 32;
            for (int i = 0; i < 4; i++) {
                bf16x8 v = *(const bf16x8*)&sTw[r * SFT + half * 32 + i * 8];
                *(bf16x8*)(dst + i * 8) = v;
            }
        } else {
            __syncthreads();  // all waves done with sT reads
            // sXT[e][r_local], r_local = 8 l x 16 h
            for (int mt = 0; mt < 2; mt++)
                for (int nt = 0; nt < 4; nt++) {
                    bf16x4 pv;
                    pv[0] = (bf16)acc[mt][nt][0]; pv[1] = (bf16)acc[mt][nt][1];
                    pv[2] = (bf16)acc[mt][nt][2]; pv[3] = (bf16)acc[mt][nt][3];
                    *(bf16x4*)&sU[(nt * 16 + m) * SXT + wq * 32 + mt * 16 + q8 * 4] = pv;
                }
            __syncthreads();
            int n = blockbase >> 15, l0 = (blockbase >> 4) & 2047;
            for (int k = 0; k < 4; k++) {
                int i = t + k * 256;
                int e = i & 63, hh = i >> 6;
                bf16x8 pv;
                for (int j = 0; j < 8; j++) pv[j] = sU[e * SXT + j * 16 + hh];
                *(bf16x8*)(Vt + ((size_t)(n * HEADS + hh) * HD + e) * SEQ + l0) = pv;
            }
        }
    }
}

// ---------------- flash attention: 32x32 MFMA, swizzled LDS K, global V ----
// Block = 4 waves x 32 q = 128 q. K tile double-buffered in LDS (XOR-swizzled
// 16B chunks -> conflict-free), 1 barrier/tile. V fragments straight from
// global (L2). No-max softmax, exp2 via pre-scaled Q; per-wave sP round-trip.
__global__ __launch_bounds__(256) void flash_kernel(
    const bf16* __restrict__ Qp, const bf16* __restrict__ Kp, const bf16* __restrict__ Vt,
    bf16* __restrict__ O) {
    int nh = blockIdx.x, qt = blockIdx.y;
    int n = nh >> 4, h = nh & 15;
    int t = threadIdx.x, lane = t & 63, wq = t >> 6;
    int l31 = lane & 31, h5 = lane >> 5;
    __shared__ __align__(16) bf16 sK[2][64 * 64];
    __shared__ __align__(16) bf16 sP[4][32 * 64];
    __shared__ float sL[4][32];
    size_t nhs = (size_t)nh;
    int qb = qt * 128 + wq * 32;
    const bf16* Qb = Qp + (nhs * SEQ + qb) * HD;
    const bf16* Kb = Kp + nhs * SEQ * HD;
    const bf16* Vb = Vt + nhs * (size_t)HD * SEQ;
    bf16* sPw = sP[wq];
    int swz = l31 & 7;

    // Q as B-operand frags: B[k=d][n=q], lane q=l31, d = kc*16 + h5*8 + j
    bf16x8 qf[4];
    for (int kc = 0; kc < 4; kc++)
        qf[kc] = *(const bf16x8*)(Qb + (size_t)l31 * HD + kc * 16 + h5 * 8);

    f32x16 z16 = {0.f, 0.f, 0.f, 0.f, 0.f, 0.f, 0.f, 0.f,
                  0.f, 0.f, 0.f, 0.f, 0.f, 0.f, 0.f, 0.f};
    f32x16 accO[2] = {z16, z16};
    float lsum = 0.f;

    // K staging map: thread -> (row, 2 chunks of 8 bf16), XOR-swizzled
    int srow = t >> 2, sc2 = t & 3;
    const bf16* sgb = Kb + (size_t)srow * HD + sc2 * 16;
    int pch0 = ((sc2 * 2) ^ (srow & 7)) * 8;
    int pch1 = ((sc2 * 2 + 1) ^ (srow & 7)) * 8;

    {   // preload tile 0
        bf16x8 g0 = *(const bf16x8*)(sgb);
        bf16x8 g1 = *(const bf16x8*)(sgb + 8);
        bf16* d = sK[0] + srow * 64;
        *(bf16x8*)(d + pch0) = g0;
        *(bf16x8*)(d + pch1) = g1;
    }
    __syncthreads();

    for (int it = 0; it < SEQ / 64; it++) {
        int kb = it * 64;
        const bf16* Kt = sK[it & 1];
        // global K loads for next tile (consumed at loop bottom)
        int kb2 = (kb + 64) & (SEQ - 1);
        bf16x8 g0 = *(const bf16x8*)(sgb + (size_t)kb2 * HD);
        bf16x8 g1 = *(const bf16x8*)(sgb + (size_t)kb2 * HD + 8);
        // S^T = K Q^T (two 32-k tiles)
        f32x16 st0 = z16, st1 = z16;
        for (int kc = 0; kc < 4; kc++) {
            bf16x8 kf0 = *(const bf16x8*)(Kt + (size_t)l31 * 64 + (((kc * 2 + h5) ^ swz) * 8));
            st0 = MFMA32(kf0, qf[kc], st0);
        }
        for (int kc = 0; kc < 4; kc++) {
            bf16x8 kf1 = *(const bf16x8*)(Kt + (size_t)(32 + l31) * 64 + (((kc * 2 + h5) ^ swz) * 8));
            st1 = MFMA32(kf1, qf[kc], st1);
        }
        // V frags from global (L2): B[k=l][n=d], lane d=l31
        bf16x8 vf[2][4];
        for (int dt = 0; dt < 2; dt++)
            for (int lc = 0; lc < 4; lc++)
                vf[dt][lc] = *(const bf16x8*)(Vb + (size_t)(dt * 32 + l31) * SEQ + kb + lc * 16 + h5 * 8);
        // p = exp2(s); pack 4 consecutive l -> b64 swizzled sP[q][l]
        for (int kt = 0; kt < 2; kt++) {
            const f32x16& st = kt ? st1 : st0;
            for (int r4 = 0; r4 < 4; r4++) {
                f32x4 p;
                p[0] = EXP2(st[r4 * 4 + 0]); p[1] = EXP2(st[r4 * 4 + 1]);
                p[2] = EXP2(st[r4 * 4 + 2]); p[3] = EXP2(st[r4 * 4 + 3]);
                lsum += p[0] + p[1] + p[2] + p[3];
                bf16x4 pb;
                pb[0] = (bf16)p[0]; pb[1] = (bf16)p[1]; pb[2] = (bf16)p[2]; pb[3] = (bf16)p[3];
                int c8 = (4 * kt + r4) ^ swz;
                *(bf16x4*)(sPw + (size_t)l31 * 64 + c8 * 8 + h5 * 4) = pb;
            }
        }
        // O += P V : A[m=q][k=l] from sP (same wave, in-order DS)
        for (int lc = 0; lc < 4; lc++) {
            bf16x8 pf = *(const bf16x8*)(sPw + (size_t)l31 * 64 + (((lc * 2 + h5) ^ swz) * 8));
            accO[0] = MFMA32(pf, vf[0][lc], accO[0]);
            accO[1] = MFMA32(pf, vf[1][lc], accO[1]);
        }
        // install next K tile into alt buffer
        bf16* d = sK[(it + 1) & 1] + srow * 64;
        *(bf16x8*)(d + pch0) = g0;
        *(bf16x8*)(d + pch1) = g1;
        __syncthreads();
    }

    // row sums: lane partial covers its l-subset of its q=l31 column
    lsum += __shfl_xor(lsum, 32);
    sL[wq][l31] = lsum;
    __syncthreads();
    for (int r4 = 0; r4 < 4; r4++) {
        f32x4 s4 = *(const f32x4*)&sL[wq][8 * r4 + 4 * h5];
        f32x4 iv;
        iv[0] = 1.f / s4[0]; iv[1] = 1.f / s4[1]; iv[2] = 1.f / s4[2]; iv[3] = 1.f / s4[3];
        for (int i = 0; i < 4; i++) {
            int qrow = qb + 8 * r4 + 4 * h5 + i;
            size_t ro = ((size_t)n * SEQ + qrow) * EMBED + h * HD;
            O[ro + l31]      = (bf16)(accO[0][r4 * 4 + i] * iv[i]);
            O[ro + 32 + l31] = (bf16)(accO[1][r4 * 4 + i] * iv[i]);
        }
    }
}

// ---------------- output projection with A/B-parity register prefetch ------
__global__ __launch_bounds__(256) void outproj_kernel(
    const bf16* __restrict__ O, const bf16* __restrict__ Wob,
    const float* __restrict__ bo, float* __restrict__ out) {
    int et = blockIdx.x, qt = blockIdx.y;
    int t = threadIdx.x, lane = t & 63, wq = t >> 6;
    int m = lane & 15, q8 = lane >> 4;
    int qb = qt * 128 + wq * 32;
    const bf16* Ob = O + (size_t)qb * EMBED;
    const bf16* Wb = Wob + (size_t)et * 64 * EMBED;
    f32x4 z = {0.f, 0.f, 0.f, 0.f};
    f32x4 acc[2][4];
    for (int a = 0; a < 2; a++)
        for (int b = 0; b < 4; b++) acc[a][b] = z;

    bf16x8 afA[2], bfA[4], afB[2], bfB[4];
    auto loadA = [&](int kk) {
        for (int mt = 0; mt < 2; mt++)
            afA[mt] = *(const bf16x8*)(Ob + (size_t)(mt * 16 + m) * EMBED + kk + q8 * 8);
        for (int nt = 0; nt < 4; nt++)
            bfA[nt] = *(const bf16x8*)(Wb + (size_t)(nt * 16 + m) * EMBED + kk + q8 * 8);
    };
    auto loadB = [&](int kk) {
        for (int mt = 0; mt < 2; mt++)
            afB[mt] = *(const bf16x8*)(Ob + (size_t)(mt * 16 + m) * EMBED + kk + q8 * 8);
        for (int nt = 0; nt < 4; nt++)
            bfB[nt] = *(const bf16x8*)(Wb + (size_t)(nt * 16 + m) * EMBED + kk + q8 * 8);
    };
    loadA(0);
    loadB(32);
    for (int kk = 0; kk < EMBED; kk += 64) {
        for (int mt = 0; mt < 2; mt++)
            for (int nt = 0; nt < 4; nt++)
                acc[mt][nt] = MFMA16(afA[mt], bfA[nt], acc[mt][nt]);
        loadA((kk + 64) & (EMBED - 1));
        for (int mt = 0; mt < 2; mt++)
            for (int nt = 0; nt < 4; nt++)
                acc[mt][nt] = MFMA16(afB[mt], bfB[nt], acc[mt][nt]);
        loadB((kk + 96) & (EMBED - 1));
    }
    for (int nt = 0; nt < 4; nt++) {
        int col = et * 64 + nt * 16 + m;
        float bias = bo[col];
        for (int mt = 0; mt < 2; mt++)
            for (int j = 0; j < 4; j++) {
                int q = qb + mt * 16 + q8 * 4 + j;
                out[(size_t)q * EMBED + col] = acc[mt][nt][j] + bias;
            }
    }
}

extern "C" void kernel_launch(void* const* d_in, const int* in_sizes, int n_in,
                              void* d_out, int out_size, void* d_ws, size_t ws_size,
                              hipStream_t stream) {
    const float* values = (const float*)d_in[0];
    const float* keys   = (const float*)d_in[1];
    const float* query  = (const float*)d_in[2];
    const float* Wv     = (const float*)d_in[3];
    const float* Wk     = (const float*)d_in[4];
    const float* Wq     = (const float*)d_in[5];
    const float* Wo     = (const float*)d_in[6];
    const float* bo     = (const float*)d_in[7];
    float* out = (float*)d_out;

    char* ws = (char*)d_ws;
    bf16* Qp  = (bf16*)(ws);
    bf16* Kp  = (bf16*)(ws + (size_t)(16 << 20));
    bf16* Vt  = (bf16*)(ws + (size_t)(32 << 20));
    bf16* O   = (bf16*)(ws + (size_t)(48 << 20));
    bf16* Wob = (bf16*)(ws + (size_t)(64 << 20));

    hipLaunchKernelGGL(proj_kernel, dim3(1024), dim3(256), 0, stream,
                       values, keys, query, Wv, Wk, Wq, Wo, Vt, Kp, Qp, Wob);
    hipLaunchKernelGGL(flash_kernel, dim3(64, 16), dim3(256), 0, stream, Qp, Kp, Vt, O);
    hipLaunchKernelGGL(outproj_kernel, dim3(16, 64), dim3(256), 0, stream, O, Wob, bo, out);
}